// Round 16
// baseline (91.287 us; speedup 1.0000x reference)
//
#include <hip/hip_runtime.h>
#include <hip/hip_bf16.h>

#define BB     64
#define NF4    200000        // NTOT / 4
#define NSEG   782           // ceil(NF4 / 256)
#define NP     128
#define NH1    256
#define NH2    128
#define NC     32
#define EPSV   1e-5f

typedef float fx4 __attribute__((ext_vector_type(4)));

__device__ __forceinline__ float dot4(fx4 a, fx4 b) {
    return fmaf(a[0], b[0], fmaf(a[1], b[1], fmaf(a[2], b[2], a[3] * b[3])));
}

// ---------------------------------------------------------------------------
// Scatter-reduce: WX[b, idx[n]] += x[b,n] * w[n]     (idx sorted)
// FILL-PATTERN structure (mimics the 7 TB/s fillBufferAligned visible in
// our own profiles): huge flat grid, 256-thr blocks, NO LDS, NO asm waits,
// ~30-instruction wave lifetime, 32 waves/CU. Each wave: 256 contiguous
// elements x 2 batch rows; masked dot (<=2 pathways per aligned 256-span),
// two interleaved 6-step shuffle reduces, ONE 2-lane atomic instruction.
// ---------------------------------------------------------------------------
__global__ __launch_bounds__(256) void k_scatter(
    const float* __restrict__ x, const float* __restrict__ w,
    const int* __restrict__ idx, float* __restrict__ WX)
{
    const int blk = blockIdx.x;
    const int b   = blk & 31;            // rows b and b+32
    const int seg = blk >> 5;            // 0..781
    const int tid = threadIdx.x;
    const int n4  = seg * 256 + tid;
    const int waveBase = seg * 256 + (tid & ~63);
    if (waveBase + 63 >= NF4) {
        if (waveBase >= NF4) return;     // fully-inactive wave (seg 781 tail)
    }
    if (n4 >= NF4) return;               // (unreachable: NF4 % 64 == 0)
    const int lane = tid & 63;

    // Wave-span pathway endpoints (sorted idx -> <=2 pathways per 256-span).
    const int  pLo = idx[waveBase * 4];
    const int  pHi = idx[waveBase * 4 + 255];
    const bool uniform = (pLo == pHi);

    const fx4  wv = reinterpret_cast<const fx4*>(w)[n4];
    const int4 pv = reinterpret_cast<const int4*>(idx)[n4];
    const fx4  xA = reinterpret_cast<const fx4*>(x)[(size_t)b * NF4 + n4];
    const fx4  xB = reinterpret_cast<const fx4*>(x)[(size_t)(b + 32) * NF4 + n4];

    fx4 wLo;
    wLo[0] = (pv.x == pLo) ? wv[0] : 0.f;
    wLo[1] = (pv.y == pLo) ? wv[1] : 0.f;
    wLo[2] = (pv.z == pLo) ? wv[2] : 0.f;
    wLo[3] = (pv.w == pLo) ? wv[3] : 0.f;

    float aLo = dot4(xA, wLo);
    float bLo = dot4(xB, wLo);
    #pragma unroll
    for (int off = 1; off < 64; off <<= 1) {   // two interleaved chains
        aLo += __shfl_xor(aLo, off);
        bLo += __shfl_xor(bLo, off);
    }

    if (uniform) {
        const float val = (lane == 0) ? aLo : bLo;
        const int   row = (lane == 0) ? b : (b + 32);
        if (lane < 2)                          // ONE atomic instruction
            atomicAdd(&WX[row * NP + pLo], val);
    } else {                                   // boundary wave (~8%)
        fx4 wHi;
        wHi[0] = (pv.x == pHi) ? wv[0] : 0.f;
        wHi[1] = (pv.y == pHi) ? wv[1] : 0.f;
        wHi[2] = (pv.z == pHi) ? wv[2] : 0.f;
        wHi[3] = (pv.w == pHi) ? wv[3] : 0.f;
        float aHi = dot4(xA, wHi);
        float bHi = dot4(xB, wHi);
        #pragma unroll
        for (int off = 1; off < 64; off <<= 1) {
            aHi += __shfl_xor(aHi, off);
            bHi += __shfl_xor(bHi, off);
        }
        const float val = (lane == 0) ? aLo : ((lane == 1) ? bLo
                        : ((lane == 2) ? aHi : bHi));
        const int   row = ((lane & 1) == 0) ? b : (b + 32);
        const int   col = (lane < 2) ? pLo : pHi;
        if (lane < 4)
            atomicAdd(&WX[row * NP + col], val);
    }
}

// ---------------------------------------------------------------------------
// Zero WX (PMC-visible).
// ---------------------------------------------------------------------------
__global__ void k_zero(float* __restrict__ WX)
{
    const int i = blockIdx.x * 256 + threadIdx.x;
    if (i < BB * NP) WX[i] = 0.f;
}

__device__ __forceinline__ float bn_shfl(float a, float gj, float bj)
{
    float s = a, q = a * a;
    #pragma unroll
    for (int off = 32; off > 0; off >>= 1) {
        s += __shfl_xor(s, off);
        q += __shfl_xor(q, off);
    }
    const float m   = s * (1.f / BB);
    const float var = q * (1.f / BB) - m * m;
    return (a - m) * rsqrtf(var + EPSV) * gj + bj;
}

// ---------------------------------------------------------------------------
// BN0+gate (redundant per block, parallel) + fc1 + ReLU + BN1.
// ---------------------------------------------------------------------------
__global__ __launch_bounds__(256) void k_fc1z(
    const float* __restrict__ WX,   const float* __restrict__ co_w,
    const float* __restrict__ bn0g, const float* __restrict__ bn0b,
    const float* __restrict__ W1,   const float* __restrict__ b1,
    const float* __restrict__ bn1g, const float* __restrict__ bn1b,
    float* __restrict__ Zout, float* __restrict__ h1t)
{
    __shared__ float Zl[NP * 65];    // pad 65: conflict-free write & read
    const int tid  = threadIdx.x;
    const int wv   = tid >> 6;
    const int lane = tid & 63;       // == batch in fc1 stage
    const int blk  = blockIdx.x;

    if (tid < NP) {
        const int p = tid;
        float sum = 0.f, sq = 0.f;
        #pragma unroll 8
        for (int b = 0; b < BB; ++b) {
            const float r = fmaxf(WX[b * NP + p], 0.f);
            sum += r; sq += r * r;
        }
        const float m   = sum * (1.f / BB);
        const float var = sq * (1.f / BB) - m * m;
        const float sc  = rsqrtf(var + EPSV) * bn0g[p];
        const float bt  = bn0b[p];
        const float sig = 1.f / (1.f + expf(-co_w[p]));
        #pragma unroll 8
        for (int b = 0; b < BB; ++b) {
            const float r = fmaxf(WX[b * NP + p], 0.f);
            const float z = ((r - m) * sc + bt) * sig;
            Zl[p * 65 + b] = z;
            if (blk == 0) Zout[b * NP + p] = z;
        }
    }
    __syncthreads();

    const int j = blk * 4 + wv;      // 0..255
    float acc = b1[j];
    #pragma unroll 8
    for (int k = 0; k < NP; ++k)
        acc = fmaf(Zl[k * 65 + lane], W1[k * NH1 + j], acc);
    h1t[j * BB + lane] = bn_shfl(fmaxf(acc, 0.f), bn1g[j], bn1b[j]);
}

// ---------------------------------------------------------------------------
// fc2 + ReLU + BN2 from TRANSPOSED input [K][BB]. One block per column j.
// ---------------------------------------------------------------------------
template <int K, int NOUT>
__global__ void k_fc_bn_t(const float* __restrict__ in_t,  // [K][BB]
                          const float* __restrict__ W,     // [K, NOUT]
                          const float* __restrict__ bias,
                          const float* __restrict__ g,
                          const float* __restrict__ beta,
                          float* __restrict__ out_t)       // [NOUT][BB]
{
    const int j = blockIdx.x;
    const int b = threadIdx.x;  // 0..63
    float acc = bias[j];
    #pragma unroll 8
    for (int k = 0; k < K; ++k)
        acc = fmaf(in_t[k * BB + b], W[k * NOUT + j], acc);
    out_t[j * BB + b] = bn_shfl(fmaxf(acc, 0.f), g[j], beta[j]);
}

// ---------------------------------------------------------------------------
// Final Linear + row softmax from transposed h2 [NH2][BB].
// ---------------------------------------------------------------------------
__global__ void k_head(const float* __restrict__ h2t,  // [NH2][BB]
                       const float* __restrict__ Wo,   // [NH2, NC]
                       const float* __restrict__ bo,
                       float* __restrict__ y)          // [BB, NC]
{
    const int b = blockIdx.x;
    const int c = threadIdx.x;  // 0..31
    float acc = bo[c];
    #pragma unroll 8
    for (int k = 0; k < NH2; ++k)
        acc = fmaf(h2t[k * BB + b], Wo[k * NC + c], acc);
    float mx = acc;
    #pragma unroll
    for (int off = 16; off > 0; off >>= 1)
        mx = fmaxf(mx, __shfl_xor(mx, off));
    const float e = expf(acc - mx);
    float s = e;
    #pragma unroll
    for (int off = 16; off > 0; off >>= 1)
        s += __shfl_xor(s, off);
    y[b * NC + c] = e / s;
}

// ---------------------------------------------------------------------------
extern "C" void kernel_launch(void* const* d_in, const int* in_sizes, int n_in,
                              void* d_out, int out_size, void* d_ws, size_t ws_size,
                              hipStream_t stream)
{
    const float* x    = (const float*)d_in[0];
    const float* w    = (const float*)d_in[1];
    const float* co_w = (const float*)d_in[2];
    const float* bn0g = (const float*)d_in[3];
    const float* bn0b = (const float*)d_in[4];
    const float* W1   = (const float*)d_in[5];
    const float* b1   = (const float*)d_in[6];
    const float* bn1g = (const float*)d_in[7];
    const float* bn1b = (const float*)d_in[8];
    const float* W2   = (const float*)d_in[9];
    const float* b2   = (const float*)d_in[10];
    const float* bn2g = (const float*)d_in[11];
    const float* bn2b = (const float*)d_in[12];
    const float* Wo   = (const float*)d_in[13];
    const float* bo   = (const float*)d_in[14];
    const int*   idx  = (const int*)d_in[15];

    float* out = (float*)d_out;
    float* y   = out;               // [64, 32]  (output 0)
    float* Z   = out + BB * NC;     // [64, 128] (output 1)

    float* WX  = (float*)d_ws;          // 8192 f32
    float* h1t = WX + BB * NP;          // 16384 f32  [j][b]
    float* h2t = h1t + BB * NH1;        // 8192 f32   [j][b]

    k_zero<<<32, 256, 0, stream>>>(WX);
    k_scatter<<<NSEG * 32, 256, 0, stream>>>(x, w, idx, WX);
    k_fc1z<<<64, 256, 0, stream>>>(WX, co_w, bn0g, bn0b,
                                   W1, b1, bn1g, bn1b, Z, h1t);
    k_fc_bn_t<NH1, NH2><<<NH2, BB, 0, stream>>>(h1t, W2, b2, bn2g, bn2b, h2t);
    k_head<<<BB, NC, 0, stream>>>(h2t, Wo, bo, y);
}